// Round 18
// baseline (133.652 us; speedup 1.0000x reference)
//
#include <hip/hip_runtime.h>
#include <hip/hip_bf16.h>

#define BN 4096
#define DD 128
#define SD 136          // padded bf16 row stride (elems)
#define NCLS 64
#define MARGIN_F 1.0f
#define NTRI 528        // 32*33/2 triangle tiles of 128x128 (bi <= bj)
#define NSLOT 64        // negp partial slots per row (row-major: negp[row*64+slot])

typedef __attribute__((ext_vector_type(8))) short bf16x8;
typedef __attribute__((ext_vector_type(4))) float f32x4;

__device__ __forceinline__ unsigned short f2bf(float f) {
    __hip_bfloat16 h = __float2bfloat16(f);
    return *reinterpret_cast<unsigned short*>(&h);
}

// K1: fp32->bf16 convert (padded stride) + row squared norms + zero counters.
__global__ __launch_bounds__(256) void prep_kernel(
    const float* __restrict__ score,
    unsigned short* __restrict__ sbf,
    float* __restrict__ mag,
    int* __restrict__ tail)
{
    const int tid = threadIdx.x;
    const int w = tid >> 6, lane = tid & 63;
    const int row = blockIdx.x * 8 + w * 2 + (lane >> 5);
    const int l32 = lane & 31;
    if (blockIdx.x == 0 && tid < 2) tail[tid] = 0;
    float4 v = *reinterpret_cast<const float4*>(score + (size_t)row * DD + l32 * 4);
    ushort4 u;
    u.x = f2bf(v.x); u.y = f2bf(v.y); u.z = f2bf(v.z); u.w = f2bf(v.w);
    *reinterpret_cast<ushort4*>(sbf + (size_t)row * SD + l32 * 4) = u;
    float s = v.x * v.x + v.y * v.y + v.z * v.z + v.w * v.w;
    #pragma unroll
    for (int o = 16; o > 0; o >>= 1) s += __shfl_xor(s, o);
    if (l32 == 0) mag[row] = s;
}

// K2: MERGED negsum (triangle tiles) + ticket-tail loss + finalize.
// Each block: tile -> fence -> ticket. Last 64 finishers run the per-class
// loss (spin is ~0 since they finished last), then dlast finalize.
__global__ __launch_bounds__(256, 2) void mega_kernel(
    const unsigned short* __restrict__ sbf,
    const float* __restrict__ mag,
    const int* __restrict__ tgt,
    float* __restrict__ negp,
    float2* __restrict__ part,
    int* __restrict__ tail,
    float* __restrict__ out)
{
    const int idx = blockIdx.x;
    const int tid = threadIdx.x;
    const int wid = tid >> 6, lane = tid & 63;
    const int lhi = lane >> 4, llo = lane & 15;
    const int wr = wid >> 1, wc = wid & 1;

    // ---------------- Phase A: triangle tile (R17 body, verbatim) ----------------
    {
        int bi = (int)((65.0f - __builtin_amdgcn_sqrtf(4225.0f - 8.0f * (float)idx)) * 0.5f);
        bi = max(0, min(bi, 31));
        while (bi * (65 - bi) / 2 > idx) --bi;
        while ((bi + 1) * (64 - bi) / 2 <= idx) ++bi;
        const int bj = bi + (idx - bi * (65 - bi) / 2);
        const bool diag = (bi == bj);

        const int i0 = bi * 128 + wr * 64;
        const int j0 = bj * 128 + wc * 64;

        f32x4 acc[4][4] = {};
        #pragma unroll
        for (int kk = 0; kk < 4; ++kk) {
            const int koff = kk * 32 + lhi * 8;
            bf16x8 a[4], b[4];
            #pragma unroll
            for (int m = 0; m < 4; ++m)
                a[m] = *reinterpret_cast<const bf16x8*>(sbf + (size_t)(i0 + m * 16 + llo) * SD + koff);
            #pragma unroll
            for (int n = 0; n < 4; ++n)
                b[n] = *reinterpret_cast<const bf16x8*>(sbf + (size_t)(j0 + n * 16 + llo) * SD + koff);
            #pragma unroll
            for (int m = 0; m < 4; ++m)
                #pragma unroll
                for (int n = 0; n < 4; ++n)
                    acc[m][n] = __builtin_amdgcn_mfma_f32_16x16x32_bf16(a[m], b[n], acc[m][n], 0, 0, 0);
        }

        float magj[4]; int tj[4];
        #pragma unroll
        for (int n = 0; n < 4; ++n) {
            const int j = j0 + n * 16 + llo;
            magj[n] = mag[j];
            tj[n] = tgt[j];
        }

        float cs[4] = {0.0f, 0.0f, 0.0f, 0.0f};
        const int rslot = bj * 2 + wc;
        #pragma unroll
        for (int m = 0; m < 4; ++m) {
            const int ibase = i0 + m * 16 + lhi * 4;
            f32x4 magi = *reinterpret_cast<const f32x4*>(mag + ibase);
            int4 ti4 = *reinterpret_cast<const int4*>(tgt + ibase);
            const int* tip = &ti4.x;
            f32x4 rs = {0.0f, 0.0f, 0.0f, 0.0f};
            #pragma unroll
            for (int r = 0; r < 4; ++r) {
                const int ti = tip[r];
                float s = 0.0f;
                #pragma unroll
                for (int n = 0; n < 4; ++n) {
                    float d2 = fmaxf(magi[r] + magj[n] - 2.0f * acc[m][n][r], 0.0f);
                    float dist = __builtin_amdgcn_sqrtf(d2);
                    float v = (ti != tj[n]) ? __expf(MARGIN_F - dist) : 0.0f;
                    s += v;
                    cs[n] += v;
                }
                #pragma unroll
                for (int o = 1; o < 16; o <<= 1) s += __shfl_xor(s, o);
                rs[r] = s;
            }
            if (llo == 0) {
                #pragma unroll
                for (int r = 0; r < 4; ++r)
                    negp[(size_t)(ibase + r) * NSLOT + rslot] = rs[r];
            }
        }

        if (!diag) {
            #pragma unroll
            for (int n = 0; n < 4; ++n) {
                cs[n] += __shfl_xor(cs[n], 16);
                cs[n] += __shfl_xor(cs[n], 32);
            }
            const int cslot = bi * 2 + wr;
            if (lhi == 0) {
                #pragma unroll
                for (int n = 0; n < 4; ++n)
                    negp[(size_t)(j0 + n * 16 + llo) * NSLOT + cslot] = cs[n];
            }
        }
    }

    // ---------------- ticket handoff ----------------
    __shared__ int sticket;
    __threadfence();                 // make this thread's negp stores device-visible
    __syncthreads();                 // all block threads fenced
    if (tid == 0) sticket = atomicAdd(&tail[0], 1);
    __syncthreads();
    const int ticket = sticket;
    if (ticket < NTRI - NCLS) return;            // not a loss block
    const int c = ticket - (NTRI - NCLS);

    if (tid == 0) {                  // wait for all tiles (we were near-last anyway)
        while (__hip_atomic_load(&tail[0], __ATOMIC_ACQUIRE, __HIP_MEMORY_SCOPE_AGENT) < NTRI)
            __builtin_amdgcn_s_sleep(1);
    }
    __syncthreads();
    __threadfence();

    // ---------------- Phase B: per-class loss (R17 body) ----------------
    __shared__ int slist[256];
    __shared__ int wsum[4];
    __shared__ int snc;
    __shared__ float sneg[256];
    int4 tv[4];
    #pragma unroll
    for (int k = 0; k < 4; ++k)
        tv[k] = *reinterpret_cast<const int4*>(tgt + tid * 16 + k * 4);
    int cnt = 0;
    #pragma unroll
    for (int k = 0; k < 4; ++k) {
        const int* q = &tv[k].x;
        #pragma unroll
        for (int e = 0; e < 4; ++e) cnt += (q[e] == c) ? 1 : 0;
    }
    int inc = cnt;
    #pragma unroll
    for (int o = 1; o < 64; o <<= 1) {
        int u = __shfl_up(inc, o);
        if (lane >= o) inc += u;
    }
    if (lane == 63) wsum[wid] = inc;
    __syncthreads();
    int wpre = 0;
    #pragma unroll
    for (int w = 0; w < 4; ++w) wpre += (w < wid) ? wsum[w] : 0;
    if (tid == 255) snc = wpre + inc;
    int pos = wpre + inc - cnt;
    #pragma unroll
    for (int k = 0; k < 4; ++k) {
        const int* q = &tv[k].x;
        #pragma unroll
        for (int e = 0; e < 4; ++e) {
            if (q[e] == c && pos < 256) { slist[pos] = tid * 16 + k * 4 + e; ++pos; }
        }
    }
    __syncthreads();
    const int n_c = snc;

    // fold negp[row][0..63] -> sneg (contiguous 16 x f32x4 per row)
    if (tid < n_c) {
        const f32x4* p = reinterpret_cast<const f32x4*>(negp + (size_t)slist[tid] * NSLOT);
        f32x4 s4 = {0.0f, 0.0f, 0.0f, 0.0f};
        #pragma unroll
        for (int k = 0; k < 16; ++k) {
            f32x4 v = p[k];
            s4[0] += v[0]; s4[1] += v[1]; s4[2] += v[2]; s4[3] += v[3];
        }
        sneg[tid] = (s4[0] + s4[1]) + (s4[2] + s4[3]);
    }
    __syncthreads();

    const int p0 = wr * 64, q0 = wc * 64;

    float lsum = 0.0f, lcnt = 0.0f;
    const bool active = (n_c > 0) && (wc >= wr) && (p0 < n_c) && (q0 < n_c);
    if (active) {
        int opA[4], opB[4], qcl[4];
        #pragma unroll
        for (int m = 0; m < 4; ++m)
            opA[m] = slist[min(p0 + m * 16 + llo, n_c - 1)];
        #pragma unroll
        for (int n = 0; n < 4; ++n) {
            qcl[n] = min(q0 + n * 16 + llo, n_c - 1);
            opB[n] = slist[qcl[n]];
        }

        f32x4 acc[4][4] = {};
        #pragma unroll
        for (int kk = 0; kk < 4; ++kk) {
            const int koff = kk * 32 + lhi * 8;
            bf16x8 a[4], b[4];
            #pragma unroll
            for (int m = 0; m < 4; ++m)
                a[m] = *reinterpret_cast<const bf16x8*>(sbf + (size_t)opA[m] * SD + koff);
            #pragma unroll
            for (int n = 0; n < 4; ++n)
                b[n] = *reinterpret_cast<const bf16x8*>(sbf + (size_t)opB[n] * SD + koff);
            #pragma unroll
            for (int m = 0; m < 4; ++m)
                #pragma unroll
                for (int n = 0; n < 4; ++n)
                    acc[m][n] = __builtin_amdgcn_mfma_f32_16x16x32_bf16(a[m], b[n], acc[m][n], 0, 0, 0);
        }

        float magjv[4], nsj[4]; int qv[4];
        #pragma unroll
        for (int n = 0; n < 4; ++n) {
            qv[n] = q0 + n * 16 + llo;
            magjv[n] = mag[opB[n]];
            nsj[n] = sneg[qcl[n]];
        }

        #pragma unroll
        for (int m = 0; m < 4; ++m) {
            #pragma unroll
            for (int r = 0; r < 4; ++r) {
                const int p = p0 + m * 16 + lhi * 4 + r;
                const bool pv = (p < n_c);
                const int pcl = min(p, n_c - 1);
                const int io = slist[pcl];
                const float magiv = mag[io];
                const float nsi = sneg[pcl];
                #pragma unroll
                for (int n = 0; n < 4; ++n) {
                    if (pv && qv[n] > p && qv[n] < n_c) {
                        float d2 = fmaxf(magiv + magjv[n] - 2.0f * acc[m][n][r], 0.0f);
                        float dist = __builtin_amdgcn_sqrtf(d2);
                        float ln = __logf(nsi + nsj[n]);
                        float uu = fmaxf(ln + dist, 0.0f);
                        lsum += uu * uu;
                        lcnt += 1.0f;
                    }
                }
            }
        }
    }

    #pragma unroll
    for (int o = 32; o > 0; o >>= 1) {
        lsum += __shfl_xor(lsum, o);
        lcnt += __shfl_xor(lcnt, o);
    }
    __shared__ float2 wpart[4];
    __shared__ int dlast;
    if (lane == 0) wpart[wid] = make_float2(lsum, lcnt);
    __syncthreads();
    if (tid == 0) {
        float s = 0.0f, cc = 0.0f;
        #pragma unroll
        for (int w = 0; w < 4; ++w) { s += wpart[w].x; cc += wpart[w].y; }
        part[c] = make_float2(s, cc);
        __threadfence();
        dlast = (atomicAdd(&tail[1], 1) == NCLS - 1) ? 1 : 0;
    }
    __syncthreads();
    if (dlast && tid < 64) {
        __threadfence();
        float2 p = part[lane];
        float s = p.x, cc = p.y;
        #pragma unroll
        for (int o = 32; o > 0; o >>= 1) {
            s += __shfl_xor(s, o);
            cc += __shfl_xor(cc, o);
        }
        if (lane == 0) out[0] = s / (2.0f * fmaxf(cc, 1.0f));
    }
}

extern "C" void kernel_launch(void* const* d_in, const int* in_sizes, int n_in,
                              void* d_out, int out_size, void* d_ws, size_t ws_size,
                              hipStream_t stream) {
    const float* score = (const float*)d_in[0];
    const int* tgt = (const int*)d_in[1];
    float* out = (float*)d_out;

    char* ws = (char*)d_ws;
    unsigned short* sbf = (unsigned short*)ws;               // 4096*136*2 ≈ 1.09 MB
    float* mag = (float*)(ws + (size_t)BN * SD * 2 + 64);    // 16 KB
    float* negp = mag + BN;                                  // 4096*64*4 = 1 MB (row-major)
    float2* part = (float2*)(negp + (size_t)BN * NSLOT);     // 512 B
    int* tail = (int*)(part + NCLS);                         // 2 ints

    prep_kernel<<<512, 256, 0, stream>>>(score, sbf, mag, tail);
    mega_kernel<<<NTRI, 256, 0, stream>>>(sbf, mag, tgt, negp, part, tail, out);
}

// Round 19
// 131.271 us; speedup vs baseline: 1.0181x; 1.0181x over previous
//
#include <hip/hip_runtime.h>
#include <hip/hip_bf16.h>

#define BN 4096
#define DD 128
#define SD 136          // padded bf16 row stride (elems)
#define NCLS 64
#define MARGIN_F 1.0f
#define NTRI 528        // 32*33/2 triangle tiles of 128x128 (bi <= bj)
#define NSLOT 64        // negp partial slots per row (row-major: negp[row*64+slot])

typedef __attribute__((ext_vector_type(8))) short bf16x8;
typedef __attribute__((ext_vector_type(4))) float f32x4;

__device__ __forceinline__ unsigned short f2bf(float f) {
    __hip_bfloat16 h = __float2bfloat16(f);
    return *reinterpret_cast<unsigned short*>(&h);
}

// K1: fp32->bf16 convert (padded stride) + row squared norms + zero counters.
__global__ __launch_bounds__(256) void prep_kernel(
    const float* __restrict__ score,
    unsigned short* __restrict__ sbf,
    float* __restrict__ mag,
    int* __restrict__ tail)
{
    const int tid = threadIdx.x;
    const int w = tid >> 6, lane = tid & 63;
    const int row = blockIdx.x * 8 + w * 2 + (lane >> 5);
    const int l32 = lane & 31;
    if (blockIdx.x == 0 && tid < 2) tail[tid] = 0;
    float4 v = *reinterpret_cast<const float4*>(score + (size_t)row * DD + l32 * 4);
    ushort4 u;
    u.x = f2bf(v.x); u.y = f2bf(v.y); u.z = f2bf(v.z); u.w = f2bf(v.w);
    *reinterpret_cast<ushort4*>(sbf + (size_t)row * SD + l32 * 4) = u;
    float s = v.x * v.x + v.y * v.y + v.z * v.z + v.w * v.w;
    #pragma unroll
    for (int o = 16; o > 0; o >>= 1) s += __shfl_xor(s, o);
    if (l32 == 0) mag[row] = s;
}

// K2: MERGED negsum (triangle tiles) + ticket-tail loss + finalize.
// Each block: tile -> fence -> ticket. Last 64 finishers run the per-class
// loss (spin is ~0 since they finished last), then dlast finalize.
__global__ __launch_bounds__(256, 2) void mega_kernel(
    const unsigned short* __restrict__ sbf,
    const float* __restrict__ mag,
    const int* __restrict__ tgt,
    float* __restrict__ negp,
    float2* __restrict__ part,
    int* __restrict__ tail,
    float* __restrict__ out)
{
    const int idx = blockIdx.x;
    const int tid = threadIdx.x;
    const int wid = tid >> 6, lane = tid & 63;
    const int lhi = lane >> 4, llo = lane & 15;
    const int wr = wid >> 1, wc = wid & 1;

    // ---------------- Phase A: triangle tile (R17 body, verbatim) ----------------
    {
        int bi = (int)((65.0f - __builtin_amdgcn_sqrtf(4225.0f - 8.0f * (float)idx)) * 0.5f);
        bi = max(0, min(bi, 31));
        while (bi * (65 - bi) / 2 > idx) --bi;
        while ((bi + 1) * (64 - bi) / 2 <= idx) ++bi;
        const int bj = bi + (idx - bi * (65 - bi) / 2);
        const bool diag = (bi == bj);

        const int i0 = bi * 128 + wr * 64;
        const int j0 = bj * 128 + wc * 64;

        f32x4 acc[4][4] = {};
        #pragma unroll
        for (int kk = 0; kk < 4; ++kk) {
            const int koff = kk * 32 + lhi * 8;
            bf16x8 a[4], b[4];
            #pragma unroll
            for (int m = 0; m < 4; ++m)
                a[m] = *reinterpret_cast<const bf16x8*>(sbf + (size_t)(i0 + m * 16 + llo) * SD + koff);
            #pragma unroll
            for (int n = 0; n < 4; ++n)
                b[n] = *reinterpret_cast<const bf16x8*>(sbf + (size_t)(j0 + n * 16 + llo) * SD + koff);
            #pragma unroll
            for (int m = 0; m < 4; ++m)
                #pragma unroll
                for (int n = 0; n < 4; ++n)
                    acc[m][n] = __builtin_amdgcn_mfma_f32_16x16x32_bf16(a[m], b[n], acc[m][n], 0, 0, 0);
        }

        float magj[4]; int tj[4];
        #pragma unroll
        for (int n = 0; n < 4; ++n) {
            const int j = j0 + n * 16 + llo;
            magj[n] = mag[j];
            tj[n] = tgt[j];
        }

        float cs[4] = {0.0f, 0.0f, 0.0f, 0.0f};
        const int rslot = bj * 2 + wc;
        #pragma unroll
        for (int m = 0; m < 4; ++m) {
            const int ibase = i0 + m * 16 + lhi * 4;
            f32x4 magi = *reinterpret_cast<const f32x4*>(mag + ibase);
            int4 ti4 = *reinterpret_cast<const int4*>(tgt + ibase);
            const int* tip = &ti4.x;
            f32x4 rs = {0.0f, 0.0f, 0.0f, 0.0f};
            #pragma unroll
            for (int r = 0; r < 4; ++r) {
                const int ti = tip[r];
                float s = 0.0f;
                #pragma unroll
                for (int n = 0; n < 4; ++n) {
                    float d2 = fmaxf(magi[r] + magj[n] - 2.0f * acc[m][n][r], 0.0f);
                    float dist = __builtin_amdgcn_sqrtf(d2);
                    float v = (ti != tj[n]) ? __expf(MARGIN_F - dist) : 0.0f;
                    s += v;
                    cs[n] += v;
                }
                #pragma unroll
                for (int o = 1; o < 16; o <<= 1) s += __shfl_xor(s, o);
                rs[r] = s;
            }
            if (llo == 0) {
                #pragma unroll
                for (int r = 0; r < 4; ++r)
                    negp[(size_t)(ibase + r) * NSLOT + rslot] = rs[r];
            }
        }

        if (!diag) {
            #pragma unroll
            for (int n = 0; n < 4; ++n) {
                cs[n] += __shfl_xor(cs[n], 16);
                cs[n] += __shfl_xor(cs[n], 32);
            }
            const int cslot = bi * 2 + wr;
            if (lhi == 0) {
                #pragma unroll
                for (int n = 0; n < 4; ++n)
                    negp[(size_t)(j0 + n * 16 + llo) * NSLOT + cslot] = cs[n];
            }
        }
    }

    // ---------------- ticket handoff ----------------
    __shared__ int sticket;
    __threadfence();                 // make this thread's negp stores device-visible
    __syncthreads();                 // all block threads fenced
    if (tid == 0) sticket = atomicAdd(&tail[0], 1);
    __syncthreads();
    const int ticket = sticket;
    if (ticket < NTRI - NCLS) return;            // not a loss block
    const int c = ticket - (NTRI - NCLS);

    if (tid == 0) {                  // wait for all tiles (we were near-last anyway)
        while (__hip_atomic_load(&tail[0], __ATOMIC_ACQUIRE, __HIP_MEMORY_SCOPE_AGENT) < NTRI)
            __builtin_amdgcn_s_sleep(1);
    }
    __syncthreads();
    __threadfence();

    // ---------------- Phase B: per-class loss (R17 body) ----------------
    __shared__ int slist[256];
    __shared__ int wsum[4];
    __shared__ int snc;
    __shared__ float sneg[256];
    int4 tv[4];
    #pragma unroll
    for (int k = 0; k < 4; ++k)
        tv[k] = *reinterpret_cast<const int4*>(tgt + tid * 16 + k * 4);
    int cnt = 0;
    #pragma unroll
    for (int k = 0; k < 4; ++k) {
        const int* q = &tv[k].x;
        #pragma unroll
        for (int e = 0; e < 4; ++e) cnt += (q[e] == c) ? 1 : 0;
    }
    int inc = cnt;
    #pragma unroll
    for (int o = 1; o < 64; o <<= 1) {
        int u = __shfl_up(inc, o);
        if (lane >= o) inc += u;
    }
    if (lane == 63) wsum[wid] = inc;
    __syncthreads();
    int wpre = 0;
    #pragma unroll
    for (int w = 0; w < 4; ++w) wpre += (w < wid) ? wsum[w] : 0;
    if (tid == 255) snc = wpre + inc;
    int pos = wpre + inc - cnt;
    #pragma unroll
    for (int k = 0; k < 4; ++k) {
        const int* q = &tv[k].x;
        #pragma unroll
        for (int e = 0; e < 4; ++e) {
            if (q[e] == c && pos < 256) { slist[pos] = tid * 16 + k * 4 + e; ++pos; }
        }
    }
    __syncthreads();
    const int n_c = snc;

    // fold negp[row][0..63] -> sneg (contiguous 16 x f32x4 per row)
    if (tid < n_c) {
        const f32x4* p = reinterpret_cast<const f32x4*>(negp + (size_t)slist[tid] * NSLOT);
        f32x4 s4 = {0.0f, 0.0f, 0.0f, 0.0f};
        #pragma unroll
        for (int k = 0; k < 16; ++k) {
            f32x4 v = p[k];
            s4[0] += v[0]; s4[1] += v[1]; s4[2] += v[2]; s4[3] += v[3];
        }
        sneg[tid] = (s4[0] + s4[1]) + (s4[2] + s4[3]);
    }
    __syncthreads();

    const int p0 = wr * 64, q0 = wc * 64;

    float lsum = 0.0f, lcnt = 0.0f;
    const bool active = (n_c > 0) && (wc >= wr) && (p0 < n_c) && (q0 < n_c);
    if (active) {
        int opA[4], opB[4], qcl[4];
        #pragma unroll
        for (int m = 0; m < 4; ++m)
            opA[m] = slist[min(p0 + m * 16 + llo, n_c - 1)];
        #pragma unroll
        for (int n = 0; n < 4; ++n) {
            qcl[n] = min(q0 + n * 16 + llo, n_c - 1);
            opB[n] = slist[qcl[n]];
        }

        f32x4 acc[4][4] = {};
        #pragma unroll
        for (int kk = 0; kk < 4; ++kk) {
            const int koff = kk * 32 + lhi * 8;
            bf16x8 a[4], b[4];
            #pragma unroll
            for (int m = 0; m < 4; ++m)
                a[m] = *reinterpret_cast<const bf16x8*>(sbf + (size_t)opA[m] * SD + koff);
            #pragma unroll
            for (int n = 0; n < 4; ++n)
                b[n] = *reinterpret_cast<const bf16x8*>(sbf + (size_t)opB[n] * SD + koff);
            #pragma unroll
            for (int m = 0; m < 4; ++m)
                #pragma unroll
                for (int n = 0; n < 4; ++n)
                    acc[m][n] = __builtin_amdgcn_mfma_f32_16x16x32_bf16(a[m], b[n], acc[m][n], 0, 0, 0);
        }

        float magjv[4], nsj[4]; int qv[4];
        #pragma unroll
        for (int n = 0; n < 4; ++n) {
            qv[n] = q0 + n * 16 + llo;
            magjv[n] = mag[opB[n]];
            nsj[n] = sneg[qcl[n]];
        }

        #pragma unroll
        for (int m = 0; m < 4; ++m) {
            #pragma unroll
            for (int r = 0; r < 4; ++r) {
                const int p = p0 + m * 16 + lhi * 4 + r;
                const bool pv = (p < n_c);
                const int pcl = min(p, n_c - 1);
                const int io = slist[pcl];
                const float magiv = mag[io];
                const float nsi = sneg[pcl];
                #pragma unroll
                for (int n = 0; n < 4; ++n) {
                    if (pv && qv[n] > p && qv[n] < n_c) {
                        float d2 = fmaxf(magiv + magjv[n] - 2.0f * acc[m][n][r], 0.0f);
                        float dist = __builtin_amdgcn_sqrtf(d2);
                        float ln = __logf(nsi + nsj[n]);
                        float uu = fmaxf(ln + dist, 0.0f);
                        lsum += uu * uu;
                        lcnt += 1.0f;
                    }
                }
            }
        }
    }

    #pragma unroll
    for (int o = 32; o > 0; o >>= 1) {
        lsum += __shfl_xor(lsum, o);
        lcnt += __shfl_xor(lcnt, o);
    }
    __shared__ float2 wpart[4];
    __shared__ int dlast;
    if (lane == 0) wpart[wid] = make_float2(lsum, lcnt);
    __syncthreads();
    if (tid == 0) {
        float s = 0.0f, cc = 0.0f;
        #pragma unroll
        for (int w = 0; w < 4; ++w) { s += wpart[w].x; cc += wpart[w].y; }
        part[c] = make_float2(s, cc);
        __threadfence();
        dlast = (atomicAdd(&tail[1], 1) == NCLS - 1) ? 1 : 0;
    }
    __syncthreads();
    if (dlast && tid < 64) {
        __threadfence();
        float2 p = part[lane];
        float s = p.x, cc = p.y;
        #pragma unroll
        for (int o = 32; o > 0; o >>= 1) {
            s += __shfl_xor(s, o);
            cc += __shfl_xor(cc, o);
        }
        if (lane == 0) out[0] = s / (2.0f * fmaxf(cc, 1.0f));
    }
}

extern "C" void kernel_launch(void* const* d_in, const int* in_sizes, int n_in,
                              void* d_out, int out_size, void* d_ws, size_t ws_size,
                              hipStream_t stream) {
    const float* score = (const float*)d_in[0];
    const int* tgt = (const int*)d_in[1];
    float* out = (float*)d_out;

    char* ws = (char*)d_ws;
    unsigned short* sbf = (unsigned short*)ws;               // 4096*136*2 ≈ 1.09 MB
    float* mag = (float*)(ws + (size_t)BN * SD * 2 + 64);    // 16 KB
    float* negp = mag + BN;                                  // 4096*64*4 = 1 MB (row-major)
    float2* part = (float2*)(negp + (size_t)BN * NSLOT);     // 512 B
    int* tail = (int*)(part + NCLS);                         // 2 ints

    prep_kernel<<<512, 256, 0, stream>>>(score, sbf, mag, tail);
    mega_kernel<<<NTRI, 256, 0, stream>>>(sbf, mag, tgt, negp, part, tail, out);
}

// Round 20
// 36.305 us; speedup vs baseline: 3.6814x; 3.6158x over previous
//
#include <hip/hip_runtime.h>
#include <hip/hip_bf16.h>

#define BN 4096
#define DD 128
#define SD 136          // padded bf16 row stride (elems)
#define NCLS 64
#define MARGIN_F 1.0f
#define NTRI 528        // 32*33/2 triangle tiles of 128x128 (bi <= bj)
#define NSLOT 64        // negp partial slots per row (row-major: negp[row*64+slot])

typedef __attribute__((ext_vector_type(8))) short bf16x8;
typedef __attribute__((ext_vector_type(4))) float f32x4;

__device__ __forceinline__ unsigned short f2bf(float f) {
    __hip_bfloat16 h = __float2bfloat16(f);
    return *reinterpret_cast<unsigned short*>(&h);
}

// K1: fp32->bf16 convert (padded stride) + row squared norms + zero tail counter.
__global__ __launch_bounds__(256) void prep_kernel(
    const float* __restrict__ score,
    unsigned short* __restrict__ sbf,
    float* __restrict__ mag,
    int* __restrict__ tail)
{
    const int tid = threadIdx.x;
    const int w = tid >> 6, lane = tid & 63;
    const int row = blockIdx.x * 8 + w * 2 + (lane >> 5);
    const int l32 = lane & 31;
    if (blockIdx.x == 0 && tid == 0) *tail = 0;
    float4 v = *reinterpret_cast<const float4*>(score + (size_t)row * DD + l32 * 4);
    ushort4 u;
    u.x = f2bf(v.x); u.y = f2bf(v.y); u.z = f2bf(v.z); u.w = f2bf(v.w);
    *reinterpret_cast<ushort4*>(sbf + (size_t)row * SD + l32 * 4) = u;
    float s = v.x * v.x + v.y * v.y + v.z * v.z + v.w * v.w;
    #pragma unroll
    for (int o = 16; o > 0; o >>= 1) s += __shfl_xor(s, o);
    if (l32 == 0) mag[row] = s;
}

// K2: neg partial sums over the TRIANGLE (bi<=bj) — R17 body + bijective
// XCD swizzle on the tile id (528 = 8 x 66) for per-XCD L2 panel locality.
__global__ __launch_bounds__(256, 2) void negsum_kernel(
    const unsigned short* __restrict__ sbf,
    const float* __restrict__ mag,
    const int* __restrict__ tgt,
    float* __restrict__ negp)
{
    const int bid = blockIdx.x;
    const int idx = (bid & 7) * 66 + (bid >> 3);   // bijective: 528 = 8*66
    const int tid = threadIdx.x;
    const int wid = tid >> 6, lane = tid & 63;
    const int lhi = lane >> 4, llo = lane & 15;
    const int wr = wid >> 1, wc = wid & 1;

    // decode triangle tile (bi <= bj); off(bi) = bi*(65-bi)/2
    int bi = (int)((65.0f - __builtin_amdgcn_sqrtf(4225.0f - 8.0f * (float)idx)) * 0.5f);
    bi = max(0, min(bi, 31));
    while (bi * (65 - bi) / 2 > idx) --bi;
    while ((bi + 1) * (64 - bi) / 2 <= idx) ++bi;
    const int bj = bi + (idx - bi * (65 - bi) / 2);
    const bool diag = (bi == bj);

    const int i0 = bi * 128 + wr * 64;
    const int j0 = bj * 128 + wc * 64;

    f32x4 acc[4][4] = {};
    #pragma unroll
    for (int kk = 0; kk < 4; ++kk) {
        const int koff = kk * 32 + lhi * 8;
        bf16x8 a[4], b[4];
        #pragma unroll
        for (int m = 0; m < 4; ++m)
            a[m] = *reinterpret_cast<const bf16x8*>(sbf + (size_t)(i0 + m * 16 + llo) * SD + koff);
        #pragma unroll
        for (int n = 0; n < 4; ++n)
            b[n] = *reinterpret_cast<const bf16x8*>(sbf + (size_t)(j0 + n * 16 + llo) * SD + koff);
        #pragma unroll
        for (int m = 0; m < 4; ++m)
            #pragma unroll
            for (int n = 0; n < 4; ++n)
                acc[m][n] = __builtin_amdgcn_mfma_f32_16x16x32_bf16(a[m], b[n], acc[m][n], 0, 0, 0);
    }

    float magj[4]; int tj[4];
    #pragma unroll
    for (int n = 0; n < 4; ++n) {
        const int j = j0 + n * 16 + llo;
        magj[n] = mag[j];
        tj[n] = tgt[j];
    }

    float cs[4] = {0.0f, 0.0f, 0.0f, 0.0f};   // per-lane partial col sums
    const int rslot = bj * 2 + wc;
    // C/D layout: col = lane&15 (j), row = (lane>>4)*4 + r (i)
    #pragma unroll
    for (int m = 0; m < 4; ++m) {
        const int ibase = i0 + m * 16 + lhi * 4;
        f32x4 magi = *reinterpret_cast<const f32x4*>(mag + ibase);
        int4 ti4 = *reinterpret_cast<const int4*>(tgt + ibase);
        const int* tip = &ti4.x;
        f32x4 rs = {0.0f, 0.0f, 0.0f, 0.0f};
        #pragma unroll
        for (int r = 0; r < 4; ++r) {
            const int ti = tip[r];
            float s = 0.0f;
            #pragma unroll
            for (int n = 0; n < 4; ++n) {
                float d2 = fmaxf(magi[r] + magj[n] - 2.0f * acc[m][n][r], 0.0f);
                float dist = __builtin_amdgcn_sqrtf(d2);
                float v = (ti != tj[n]) ? __expf(MARGIN_F - dist) : 0.0f;
                s += v;
                cs[n] += v;
            }
            #pragma unroll
            for (int o = 1; o < 16; o <<= 1) s += __shfl_xor(s, o);
            rs[r] = s;
        }
        if (llo == 0) {
            #pragma unroll
            for (int r = 0; r < 4; ++r)
                negp[(size_t)(ibase + r) * NSLOT + rslot] = rs[r];
        }
    }

    if (!diag) {
        // complete col sums over the wave's 64 rows (reduce across lhi groups)
        #pragma unroll
        for (int n = 0; n < 4; ++n) {
            cs[n] += __shfl_xor(cs[n], 16);
            cs[n] += __shfl_xor(cs[n], 32);
        }
        const int cslot = bi * 2 + wr;
        if (lhi == 0) {
            #pragma unroll
            for (int n = 0; n < 4; ++n)
                negp[(size_t)(j0 + n * 16 + llo) * NSLOT + cslot] = cs[n];
        }
    }
}

// K3: per-class loss: compaction + contiguous negp fold + loss body +
// tail-block finalize (3-launch pipeline).
__global__ __launch_bounds__(256) void loss_kernel(
    const unsigned short* __restrict__ sbf,
    const float* __restrict__ mag,
    const float* __restrict__ negp,
    const int* __restrict__ tgt,
    float2* __restrict__ part,
    int* __restrict__ tail,
    float* __restrict__ out)
{
    const int c = blockIdx.x;
    const int tid = threadIdx.x;
    const int wid = tid >> 6, lane = tid & 63;

    // ---- stable compaction of rows with tgt==c into slist ----
    __shared__ int slist[256];
    __shared__ int wsum[4];
    __shared__ int snc;
    __shared__ float sneg[256];
    int4 tv[4];
    #pragma unroll
    for (int k = 0; k < 4; ++k)
        tv[k] = *reinterpret_cast<const int4*>(tgt + tid * 16 + k * 4);
    int cnt = 0;
    #pragma unroll
    for (int k = 0; k < 4; ++k) {
        const int* q = &tv[k].x;
        #pragma unroll
        for (int e = 0; e < 4; ++e) cnt += (q[e] == c) ? 1 : 0;
    }
    int inc = cnt;
    #pragma unroll
    for (int o = 1; o < 64; o <<= 1) {
        int u = __shfl_up(inc, o);
        if (lane >= o) inc += u;
    }
    if (lane == 63) wsum[wid] = inc;
    __syncthreads();
    int wpre = 0;
    #pragma unroll
    for (int w = 0; w < 4; ++w) wpre += (w < wid) ? wsum[w] : 0;
    if (tid == 255) snc = wpre + inc;
    int pos = wpre + inc - cnt;
    #pragma unroll
    for (int k = 0; k < 4; ++k) {
        const int* q = &tv[k].x;
        #pragma unroll
        for (int e = 0; e < 4; ++e) {
            if (q[e] == c && pos < 256) { slist[pos] = tid * 16 + k * 4 + e; ++pos; }
        }
    }
    __syncthreads();
    const int n_c = snc;

    // ---- fold negp[row][0..63] -> sneg (contiguous 16 x f32x4 per row) ----
    if (tid < n_c) {
        const f32x4* p = reinterpret_cast<const f32x4*>(negp + (size_t)slist[tid] * NSLOT);
        f32x4 s4 = {0.0f, 0.0f, 0.0f, 0.0f};
        #pragma unroll
        for (int k = 0; k < 16; ++k) {
            f32x4 v = p[k];
            s4[0] += v[0]; s4[1] += v[1]; s4[2] += v[2]; s4[3] += v[3];
        }
        sneg[tid] = (s4[0] + s4[1]) + (s4[2] + s4[3]);
    }
    __syncthreads();

    const int wr = wid >> 1, wc = wid & 1;
    const int p0 = wr * 64, q0 = wc * 64;
    const int lhi = lane >> 4, llo = lane & 15;

    float lsum = 0.0f, lcnt = 0.0f;
    const bool active = (n_c > 0) && (wc >= wr) && (p0 < n_c) && (q0 < n_c);
    if (active) {
        int opA[4], opB[4], qcl[4];
        #pragma unroll
        for (int m = 0; m < 4; ++m)
            opA[m] = slist[min(p0 + m * 16 + llo, n_c - 1)];
        #pragma unroll
        for (int n = 0; n < 4; ++n) {
            qcl[n] = min(q0 + n * 16 + llo, n_c - 1);
            opB[n] = slist[qcl[n]];
        }

        f32x4 acc[4][4] = {};
        #pragma unroll
        for (int kk = 0; kk < 4; ++kk) {
            const int koff = kk * 32 + lhi * 8;
            bf16x8 a[4], b[4];
            #pragma unroll
            for (int m = 0; m < 4; ++m)
                a[m] = *reinterpret_cast<const bf16x8*>(sbf + (size_t)opA[m] * SD + koff);
            #pragma unroll
            for (int n = 0; n < 4; ++n)
                b[n] = *reinterpret_cast<const bf16x8*>(sbf + (size_t)opB[n] * SD + koff);
            #pragma unroll
            for (int m = 0; m < 4; ++m)
                #pragma unroll
                for (int n = 0; n < 4; ++n)
                    acc[m][n] = __builtin_amdgcn_mfma_f32_16x16x32_bf16(a[m], b[n], acc[m][n], 0, 0, 0);
        }

        float magjv[4], nsj[4]; int qv[4];
        #pragma unroll
        for (int n = 0; n < 4; ++n) {
            qv[n] = q0 + n * 16 + llo;
            magjv[n] = mag[opB[n]];
            nsj[n] = sneg[qcl[n]];
        }

        #pragma unroll
        for (int m = 0; m < 4; ++m) {
            #pragma unroll
            for (int r = 0; r < 4; ++r) {
                const int p = p0 + m * 16 + lhi * 4 + r;
                const bool pv = (p < n_c);
                const int pcl = min(p, n_c - 1);
                const int io = slist[pcl];
                const float magiv = mag[io];
                const float nsi = sneg[pcl];
                #pragma unroll
                for (int n = 0; n < 4; ++n) {
                    if (pv && qv[n] > p && qv[n] < n_c) {
                        float d2 = fmaxf(magiv + magjv[n] - 2.0f * acc[m][n][r], 0.0f);
                        float dist = __builtin_amdgcn_sqrtf(d2);
                        float ln = __logf(nsi + nsj[n]);
                        float uu = fmaxf(ln + dist, 0.0f);
                        lsum += uu * uu;
                        lcnt += 1.0f;
                    }
                }
            }
        }
    }

    #pragma unroll
    for (int o = 32; o > 0; o >>= 1) {
        lsum += __shfl_xor(lsum, o);
        lcnt += __shfl_xor(lcnt, o);
    }
    __shared__ float2 wpart[4];
    __shared__ int dlast;
    if (lane == 0) wpart[wid] = make_float2(lsum, lcnt);
    __syncthreads();
    if (tid == 0) {
        float s = 0.0f, cc = 0.0f;
        #pragma unroll
        for (int w = 0; w < 4; ++w) { s += wpart[w].x; cc += wpart[w].y; }
        part[c] = make_float2(s, cc);
        __threadfence();
        dlast = (atomicAdd(tail, 1) == NCLS - 1) ? 1 : 0;
    }
    __syncthreads();
    if (dlast && tid < 64) {
        __threadfence();
        float2 p = part[lane];
        float s = p.x, cc = p.y;
        #pragma unroll
        for (int o = 32; o > 0; o >>= 1) {
            s += __shfl_xor(s, o);
            cc += __shfl_xor(cc, o);
        }
        if (lane == 0) out[0] = s / (2.0f * fmaxf(cc, 1.0f));
    }
}

extern "C" void kernel_launch(void* const* d_in, const int* in_sizes, int n_in,
                              void* d_out, int out_size, void* d_ws, size_t ws_size,
                              hipStream_t stream) {
    const float* score = (const float*)d_in[0];
    const int* tgt = (const int*)d_in[1];
    float* out = (float*)d_out;

    char* ws = (char*)d_ws;
    unsigned short* sbf = (unsigned short*)ws;               // 4096*136*2 ≈ 1.09 MB
    float* mag = (float*)(ws + (size_t)BN * SD * 2 + 64);    // 16 KB
    float* negp = mag + BN;                                  // 4096*64*4 = 1 MB (row-major)
    float2* part = (float2*)(negp + (size_t)BN * NSLOT);     // 512 B
    int* tail = (int*)(part + NCLS);                         // 1 int

    prep_kernel<<<512, 256, 0, stream>>>(score, sbf, mag, tail);
    negsum_kernel<<<NTRI, 256, 0, stream>>>(sbf, mag, tgt, negp);
    loss_kernel<<<NCLS, 256, 0, stream>>>(sbf, mag, negp, tgt, part, tail, out);
}